// Round 8
// baseline (49.248 us; speedup 1.0000x reference)
//
#include <hip/hip_runtime.h>

typedef float f32x4 __attribute__((ext_vector_type(4)));
typedef float f32x16 __attribute__((ext_vector_type(16)));
typedef _Float16 f16x8 __attribute__((ext_vector_type(8)));
typedef __fp16 fp16x2 __attribute__((ext_vector_type(2)));
typedef int i32x2 __attribute__((ext_vector_type(2)));

static __device__ __forceinline__ unsigned pk2(float a, float b) {
    fp16x2 r = __builtin_amdgcn_cvt_pkrtz(a, b); // v_cvt_pkrtz_f16_f32
    return __builtin_bit_cast(unsigned, r);
}

#define MFMA32(A, B, C) __builtin_amdgcn_mfma_f32_32x32x16_f16((A), (B), (C), 0, 0, 0)

// qkv: [2][2048][3][16][64] f32; layout: [128][8] i32; out: [2][2048][16][64] f32
// wg = 256 thr = 4 waves (qw, ks): q-rows [64*wgq + 32*qw, +32), key-chunk ks of each
// 64-key tile. 1024 wgs x 4 waves = 4096 waves (4/SIMD) vs round-7's 2048 (2/SIMD).
// Fixed-base softmax (additive partials) -> ks-pair partial acc/lsum combined via LDS
// at the end. S^T = mfma_32x32x16(K,Q^T); P in-register (cvt_pkrtz+permlane32_swap);
// O^T = mfma_32x32x16(V^T,P^T). Q pre-scaled by 0.125*log2(e) -> p = exp2(st).
__global__ __launch_bounds__(256, 4) void fba_fwd(const float* __restrict__ qkv,
                                                  const int* __restrict__ layout,
                                                  float* __restrict__ out) {
    __shared__ unsigned short Klds[2][64 * 64];  // [key][d] f16, byte ^= (key&7)<<4
    __shared__ unsigned short Vtlds[2][64 * 64]; // [d][key] f16, byte ^= ((d^(d>>3))&7)<<4

    const int bid = blockIdx.x;
    const int vid = (bid & 7) * 128 + (bid >> 3); // XCD swizzle: one (b,h) per XCD
    const int b = vid >> 9;
    const int hh = (vid >> 5) & 15;
    const int j = (vid >> 2) & 7;
    const int qs = vid & 3;

    const int tid = threadIdx.x;
    const int w = tid >> 6;
    const int qw = w >> 1;      // q-half of the wg's 64 rows
    const int ks = w & 1;       // key-chunk (32 keys) this wave owns
    const int lane = tid & 63;
    const int l31 = lane & 31;
    const int h = lane >> 5;

    const size_t bbase = (size_t)b * 2048 * 3072;
    const int qbase = 256 * j + 64 * qs + 32 * qw;

    // active K-blocks (uniform): pack active kb ids into nibbles
    unsigned kbl = 0; int nact = 0;
    for (int kb = 0; kb < 8; ++kb) {
        int a = 0;
        #pragma unroll
        for (int r = 0; r < 4; ++r) a |= layout[(16 * j + 4 * qs + r) * 8 + kb];
        if (a) { kbl |= (unsigned)kb << (4 * nact); ++nact; }
    }
    const int ntile = 4 * nact; // 64-key tiles

    // Q frags (B-operand, pre-scaled): lane -> Q[q=qbase+l31][d = ds*16+8h+e] * SC
    const float SC = 0.18033688f; // 0.125 * log2(e)
    f16x8 qf[4];
    {
        const float* qp = qkv + bbase + (size_t)(qbase + l31) * 3072 + hh * 64;
        #pragma unroll
        for (int ds = 0; ds < 4; ++ds) {
            const float* p0 = qp + ds * 16 + 8 * h;
            float4 x = *(const float4*)p0;
            float4 y = *(const float4*)(p0 + 4);
            uint4 u;
            u.x = pk2(x.x * SC, x.y * SC); u.y = pk2(x.z * SC, x.w * SC);
            u.z = pk2(y.x * SC, y.y * SC); u.w = pk2(y.z * SC, y.w * SC);
            qf[ds] = __builtin_bit_cast(f16x8, u);
        }
    }

    f32x16 acc[2]; // [dt]: partial O^T[d = dt*32 + (r&3)+8*(r>>2)+4h][q=l31] over own keys
    acc[0] = (f32x16)(0.f);
    acc[1] = (f32x16)(0.f);
    float lsum = 0.f;

    // staging thread-constants (256 threads)
    const int skey = tid >> 4;  // 0..15
    const int sdc  = tid & 15;  // d-group of 4 floats

    float4 kr0, kr1, kr2, kr3;  // K prefetch: keys skey+16m
    float4 va0, vb0, va1, vb1;  // V prefetch: keys 2skey+32m, +1

#define STAGE_LOAD(ks_) {                                                           \
    const float* kp_ = qkv + bbase + (size_t)((ks_) + skey) * 3072 + 1024 + hh * 64 + sdc * 4; \
    kr0 = *(const float4*)kp_;                                                      \
    kr1 = *(const float4*)(kp_ + 16 * 3072);                                        \
    kr2 = *(const float4*)(kp_ + 32 * 3072);                                        \
    kr3 = *(const float4*)(kp_ + 48 * 3072);                                        \
    const float* vp_ = qkv + bbase + (size_t)((ks_) + 2 * skey) * 3072 + 2048 + hh * 64 + sdc * 4; \
    va0 = *(const float4*)vp_;               vb0 = *(const float4*)(vp_ +      3072); \
    va1 = *(const float4*)(vp_ + 32 * 3072); vb1 = *(const float4*)(vp_ + 33 * 3072); \
}

#define WK(m, krm) *(uint2*)((char*)KB + ((((skey + 16 * (m)) * 128 + sdc * 8)) ^ ((skey & 7) << 4))) = \
    make_uint2(pk2(krm.x, krm.y), pk2(krm.z, krm.w));
#define WV(m, vam, vbm) {                                                           \
    const float* a_ = &vam.x; const float* b_ = &vbm.x;                             \
    _Pragma("unroll")                                                               \
    for (int e2 = 0; e2 < 4; ++e2) {                                                \
        int d_ = 4 * sdc + e2;                                                      \
        int off_ = (d_ * 128 + (2 * skey + 32 * (m)) * 2) ^ (((d_ ^ (d_ >> 3)) & 7) << 4); \
        *(unsigned*)((char*)VB + off_) = pk2(a_[e2], b_[e2]);                       \
    }                                                                               \
}
#define STAGE_WRITE(nb) {                                                           \
    unsigned short* KB = &Klds[nb][0];                                              \
    WK(0, kr0) WK(1, kr1) WK(2, kr2) WK(3, kr3)                                     \
    unsigned short* VB = &Vtlds[nb][0];                                             \
    WV(0, va0, vb0) WV(1, va1, vb1)                                                 \
}

    { // prologue: tile 0
        int kb0 = kbl & 15;
        STAGE_LOAD(kb0 * 256);
        STAGE_WRITE(0);
    }
    __syncthreads();

    for (int t = 0; t < ntile; ++t) {
        const bool more = (t + 1 < ntile);
        if (more) { // issue next tile's globals early (named regs), write after compute
            int t2 = t + 1;
            int kb = (kbl >> (4 * (t2 >> 2))) & 15;
            STAGE_LOAD(kb * 256 + (t2 & 3) * 64);
        }
        {
            const int cur = t & 1;
            const unsigned short* KB = &Klds[cur][0];
            const unsigned short* VB = &Vtlds[cur][0];
            // this wave computes only its 32-key chunk (kt = ks)
            const int key = ks * 32 + l31;
            const int kswz = (l31 & 7) << 4;
            f16x8 kf[4];
            #pragma unroll
            for (int ds = 0; ds < 4; ++ds)
                kf[ds] = *(const f16x8*)((const char*)KB + ((key * 128 + ds * 32 + h * 16) ^ kswz));
            f16x8 vf[2][2]; // [dt][ksi]
            #pragma unroll
            for (int dt = 0; dt < 2; ++dt) {
                const int d = dt * 32 + l31;
                const int vswz = ((d ^ (d >> 3)) & 7) << 4;
                #pragma unroll
                for (int ksi = 0; ksi < 2; ++ksi)
                    vf[dt][ksi] = *(const f16x8*)((const char*)VB + ((d * 128 + ks * 64 + ksi * 32 + h * 16) ^ vswz));
            }
            // S^T[key][q], q = l31: chain over 4 d-slices
            f32x16 st = (f32x16)(0.f);
            st = MFMA32(kf[0], qf[0], st);
            st = MFMA32(kf[1], qf[1], st);
            st = MFMA32(kf[2], qf[2], st);
            st = MFMA32(kf[3], qf[3], st);
            // p = exp2(st) (Q pre-scaled); pack quads for permlane exchange
            unsigned ulo[4], uhi[4];
            float psum = 0.f;
            #pragma unroll
            for (int jq = 0; jq < 4; ++jq) {
                float a0 = exp2f(st[4 * jq + 0]);
                float a1 = exp2f(st[4 * jq + 1]);
                float a2 = exp2f(st[4 * jq + 2]);
                float a3 = exp2f(st[4 * jq + 3]);
                psum += (a0 + a1) + (a2 + a3);
                ulo[jq] = pk2(a0, a1);
                uhi[jq] = pk2(a2, a3);
            }
            lsum += psum;
            // B-frags of P^T via permlane32_swap (vdst'[32+i]=vsrc[i], vsrc'[i]=vdst[32+i])
            #pragma unroll
            for (int ksi = 0; ksi < 2; ++ksi) {
                i32x2 r0 = __builtin_amdgcn_permlane32_swap((int)ulo[2 * ksi], (int)ulo[2 * ksi + 1], false, false);
                i32x2 r1 = __builtin_amdgcn_permlane32_swap((int)uhi[2 * ksi], (int)uhi[2 * ksi + 1], false, false);
                uint4 uw;
                uw.x = (unsigned)r0[0]; uw.y = (unsigned)r1[0];
                uw.z = (unsigned)r0[1]; uw.w = (unsigned)r1[1];
                f16x8 pf = __builtin_bit_cast(f16x8, uw);
                acc[0] = MFMA32(vf[0][ksi], pf, acc[0]);
                acc[1] = MFMA32(vf[1][ksi], pf, acc[1]);
            }
        }
        if (more) STAGE_WRITE((t + 1) & 1); // vmcnt drained under compute
        __syncthreads();
    }

    // ---- combine ks-pair partials via LDS (reuse K/V buffers), then store
    lsum += __shfl_xor(lsum, 32); // h-halves hold complementary keys of the chunk
    float* sh = (qw == 0) ? (float*)&Klds[0][0] : (float*)&Vtlds[0][0];
    if (ks == 1) {
        float* p = sh + lane * 34; // stride 34 f32: bank = 2*lane mod 32 -> 2-way (free)
        #pragma unroll
        for (int i = 0; i < 16; ++i) p[i] = acc[0][i];
        #pragma unroll
        for (int i = 0; i < 16; ++i) p[16 + i] = acc[1][i];
        p[32] = lsum;
    }
    __syncthreads();
    if (ks == 0) {
        const float* p = sh + lane * 34;
        #pragma unroll
        for (int i = 0; i < 16; ++i) acc[0][i] += p[i];
        #pragma unroll
        for (int i = 0; i < 16; ++i) acc[1][i] += p[16 + i];
        lsum += p[32];
        const float inv = 1.0f / lsum;
        float* op = out + (((size_t)b * 2048 + (qbase + l31)) * 16 + hh) * 64;
        #pragma unroll
        for (int dt = 0; dt < 2; ++dt)
            #pragma unroll
            for (int jq = 0; jq < 4; ++jq) {
                float4 o;
                o.x = acc[dt][4 * jq + 0] * inv;
                o.y = acc[dt][4 * jq + 1] * inv;
                o.z = acc[dt][4 * jq + 2] * inv;
                o.w = acc[dt][4 * jq + 3] * inv;
                *(float4*)(op + dt * 32 + 8 * jq + 4 * h) = o;
            }
    }
}

extern "C" void kernel_launch(void* const* d_in, const int* in_sizes, int n_in,
                              void* d_out, int out_size, void* d_ws, size_t ws_size,
                              hipStream_t stream) {
    const float* qkv = (const float*)d_in[0];
    const int* layout = (const int*)d_in[1];
    float* out = (float*)d_out;
    fba_fwd<<<dim3(1024), dim3(256), 0, stream>>>(qkv, layout, out);
}

// Round 9
// 32.130 us; speedup vs baseline: 1.5328x; 1.5328x over previous
//
#include <hip/hip_runtime.h>

typedef float f32x4 __attribute__((ext_vector_type(4)));
typedef float f32x16 __attribute__((ext_vector_type(16)));
typedef _Float16 f16x8 __attribute__((ext_vector_type(8)));
typedef __fp16 fp16x2 __attribute__((ext_vector_type(2)));
typedef int i32x2 __attribute__((ext_vector_type(2)));

static __device__ __forceinline__ unsigned pk2(float a, float b) {
    fp16x2 r = __builtin_amdgcn_cvt_pkrtz(a, b); // v_cvt_pkrtz_f16_f32
    return __builtin_bit_cast(unsigned, r);
}

#define MFMA32(A, B, C) __builtin_amdgcn_mfma_f32_32x32x16_f16((A), (B), (C), 0, 0, 0)

// qkv: [2][2048][3][16][64] f32; layout: [128][8] i32; out: [2][2048][16][64] f32
// wg = 256 thr = 4 waves (qw, ks): q-rows [64*wgq + 32*qw, +32), key-chunk ks of each
// 64-key tile. Fixed-base softmax (additive partials) -> ks-pair partials combined via
// LDS at the end. S^T = mfma_32x32x16(K,Q^T); P in-register (cvt_pkrtz+permlane32_swap);
// O^T = mfma_32x32x16(V^T,P^T). Q pre-scaled by 0.125*log2(e) -> p = exp2(st).
// launch_bounds(256,2): kernel needs ~150-170 VGPR; round-8's (256,4) cap of 128 caused
// scratch spill (+36 MB HBM traffic, VGPR squeezed to 64). Cap 256 -> no spill; HW
// self-selects ~3 waves/SIMD from actual VGPR use.
__global__ __launch_bounds__(256, 2) void fba_fwd(const float* __restrict__ qkv,
                                                  const int* __restrict__ layout,
                                                  float* __restrict__ out) {
    __shared__ unsigned short Klds[2][64 * 64];  // [key][d] f16, byte ^= (key&7)<<4
    __shared__ unsigned short Vtlds[2][64 * 64]; // [d][key] f16, byte ^= ((d^(d>>3))&7)<<4

    const int bid = blockIdx.x;
    const int vid = (bid & 7) * 128 + (bid >> 3); // XCD swizzle: one (b,h) per XCD
    const int b = vid >> 9;
    const int hh = (vid >> 5) & 15;
    const int j = (vid >> 2) & 7;
    const int qs = vid & 3;

    const int tid = threadIdx.x;
    const int w = tid >> 6;
    const int qw = w >> 1;      // q-half of the wg's 64 rows
    const int ks = w & 1;       // key-chunk (32 keys) this wave owns
    const int lane = tid & 63;
    const int l31 = lane & 31;
    const int h = lane >> 5;

    const size_t bbase = (size_t)b * 2048 * 3072;
    const int qbase = 256 * j + 64 * qs + 32 * qw;

    // active K-blocks (uniform): pack active kb ids into nibbles
    unsigned kbl = 0; int nact = 0;
    for (int kb = 0; kb < 8; ++kb) {
        int a = 0;
        #pragma unroll
        for (int r = 0; r < 4; ++r) a |= layout[(16 * j + 4 * qs + r) * 8 + kb];
        if (a) { kbl |= (unsigned)kb << (4 * nact); ++nact; }
    }
    const int ntile = 4 * nact; // 64-key tiles

    // Q frags (B-operand, pre-scaled): lane -> Q[q=qbase+l31][d = ds*16+8h+e] * SC
    const float SC = 0.18033688f; // 0.125 * log2(e)
    f16x8 qf[4];
    {
        const float* qp = qkv + bbase + (size_t)(qbase + l31) * 3072 + hh * 64;
        #pragma unroll
        for (int ds = 0; ds < 4; ++ds) {
            const float* p0 = qp + ds * 16 + 8 * h;
            float4 x = *(const float4*)p0;
            float4 y = *(const float4*)(p0 + 4);
            uint4 u;
            u.x = pk2(x.x * SC, x.y * SC); u.y = pk2(x.z * SC, x.w * SC);
            u.z = pk2(y.x * SC, y.y * SC); u.w = pk2(y.z * SC, y.w * SC);
            qf[ds] = __builtin_bit_cast(f16x8, u);
        }
    }

    f32x16 acc[2]; // [dt]: partial O^T[d = dt*32 + (r&3)+8*(r>>2)+4h][q=l31] over own keys
    acc[0] = (f32x16)(0.f);
    acc[1] = (f32x16)(0.f);
    float lsum = 0.f;

    // staging thread-constants (256 threads)
    const int skey = tid >> 4;  // 0..15
    const int sdc  = tid & 15;  // d-group of 4 floats

    float4 kr0, kr1, kr2, kr3;  // K prefetch: keys skey+16m
    float4 va0, vb0, va1, vb1;  // V prefetch: keys 2skey+32m, +1

#define STAGE_LOAD(ks_) {                                                           \
    const float* kp_ = qkv + bbase + (size_t)((ks_) + skey) * 3072 + 1024 + hh * 64 + sdc * 4; \
    kr0 = *(const float4*)kp_;                                                      \
    kr1 = *(const float4*)(kp_ + 16 * 3072);                                        \
    kr2 = *(const float4*)(kp_ + 32 * 3072);                                        \
    kr3 = *(const float4*)(kp_ + 48 * 3072);                                        \
    const float* vp_ = qkv + bbase + (size_t)((ks_) + 2 * skey) * 3072 + 2048 + hh * 64 + sdc * 4; \
    va0 = *(const float4*)vp_;               vb0 = *(const float4*)(vp_ +      3072); \
    va1 = *(const float4*)(vp_ + 32 * 3072); vb1 = *(const float4*)(vp_ + 33 * 3072); \
}

#define WK(m, krm) *(uint2*)((char*)KB + ((((skey + 16 * (m)) * 128 + sdc * 8)) ^ ((skey & 7) << 4))) = \
    make_uint2(pk2(krm.x, krm.y), pk2(krm.z, krm.w));
#define WV(m, vam, vbm) {                                                           \
    const float* a_ = &vam.x; const float* b_ = &vbm.x;                             \
    _Pragma("unroll")                                                               \
    for (int e2 = 0; e2 < 4; ++e2) {                                                \
        int d_ = 4 * sdc + e2;                                                      \
        int off_ = (d_ * 128 + (2 * skey + 32 * (m)) * 2) ^ (((d_ ^ (d_ >> 3)) & 7) << 4); \
        *(unsigned*)((char*)VB + off_) = pk2(a_[e2], b_[e2]);                       \
    }                                                                               \
}
#define STAGE_WRITE(nb) {                                                           \
    unsigned short* KB = &Klds[nb][0];                                              \
    WK(0, kr0) WK(1, kr1) WK(2, kr2) WK(3, kr3)                                     \
    unsigned short* VB = &Vtlds[nb][0];                                             \
    WV(0, va0, vb0) WV(1, va1, vb1)                                                 \
}

    { // prologue: tile 0
        int kb0 = kbl & 15;
        STAGE_LOAD(kb0 * 256);
        STAGE_WRITE(0);
    }
    __syncthreads();

    for (int t = 0; t < ntile; ++t) {
        const bool more = (t + 1 < ntile);
        if (more) { // issue next tile's globals early (named regs), write after compute
            int t2 = t + 1;
            int kb = (kbl >> (4 * (t2 >> 2))) & 15;
            STAGE_LOAD(kb * 256 + (t2 & 3) * 64);
        }
        {
            const int cur = t & 1;
            const unsigned short* KB = &Klds[cur][0];
            const unsigned short* VB = &Vtlds[cur][0];
            // this wave computes only its 32-key chunk (kt = ks)
            const int key = ks * 32 + l31;
            const int kswz = (l31 & 7) << 4;
            f16x8 kf[4];
            #pragma unroll
            for (int ds = 0; ds < 4; ++ds)
                kf[ds] = *(const f16x8*)((const char*)KB + ((key * 128 + ds * 32 + h * 16) ^ kswz));
            f16x8 vf[2][2]; // [dt][ksi]
            #pragma unroll
            for (int dt = 0; dt < 2; ++dt) {
                const int d = dt * 32 + l31;
                const int vswz = ((d ^ (d >> 3)) & 7) << 4;
                #pragma unroll
                for (int ksi = 0; ksi < 2; ++ksi)
                    vf[dt][ksi] = *(const f16x8*)((const char*)VB + ((d * 128 + ks * 64 + ksi * 32 + h * 16) ^ vswz));
            }
            // S^T[key][q], q = l31: chain over 4 d-slices
            f32x16 st = (f32x16)(0.f);
            st = MFMA32(kf[0], qf[0], st);
            st = MFMA32(kf[1], qf[1], st);
            st = MFMA32(kf[2], qf[2], st);
            st = MFMA32(kf[3], qf[3], st);
            // p = exp2(st) (Q pre-scaled); pack quads for permlane exchange
            unsigned ulo[4], uhi[4];
            float psum = 0.f;
            #pragma unroll
            for (int jq = 0; jq < 4; ++jq) {
                float a0 = exp2f(st[4 * jq + 0]);
                float a1 = exp2f(st[4 * jq + 1]);
                float a2 = exp2f(st[4 * jq + 2]);
                float a3 = exp2f(st[4 * jq + 3]);
                psum += (a0 + a1) + (a2 + a3);
                ulo[jq] = pk2(a0, a1);
                uhi[jq] = pk2(a2, a3);
            }
            lsum += psum;
            // B-frags of P^T via permlane32_swap (vdst'[32+i]=vsrc[i], vsrc'[i]=vdst[32+i])
            #pragma unroll
            for (int ksi = 0; ksi < 2; ++ksi) {
                i32x2 r0 = __builtin_amdgcn_permlane32_swap((int)ulo[2 * ksi], (int)ulo[2 * ksi + 1], false, false);
                i32x2 r1 = __builtin_amdgcn_permlane32_swap((int)uhi[2 * ksi], (int)uhi[2 * ksi + 1], false, false);
                uint4 uw;
                uw.x = (unsigned)r0[0]; uw.y = (unsigned)r1[0];
                uw.z = (unsigned)r0[1]; uw.w = (unsigned)r1[1];
                f16x8 pf = __builtin_bit_cast(f16x8, uw);
                acc[0] = MFMA32(vf[0][ksi], pf, acc[0]);
                acc[1] = MFMA32(vf[1][ksi], pf, acc[1]);
            }
        }
        if (more) STAGE_WRITE((t + 1) & 1); // vmcnt drained under compute
        __syncthreads();
    }

    // ---- combine ks-pair partials via LDS (reuse K/V buffers), then store
    lsum += __shfl_xor(lsum, 32); // h-halves hold complementary keys of the chunk
    float* sh = (qw == 0) ? (float*)&Klds[0][0] : (float*)&Vtlds[0][0];
    if (ks == 1) {
        float* p = sh + lane * 33; // stride 33 f32: bank = lane mod 32 -> 2-way (free)
        #pragma unroll
        for (int i = 0; i < 16; ++i) p[i] = acc[0][i];
        #pragma unroll
        for (int i = 0; i < 16; ++i) p[16 + i] = acc[1][i];
        p[32] = lsum;
    }
    __syncthreads();
    if (ks == 0) {
        const float* p = sh + lane * 33;
        #pragma unroll
        for (int i = 0; i < 16; ++i) acc[0][i] += p[i];
        #pragma unroll
        for (int i = 0; i < 16; ++i) acc[1][i] += p[16 + i];
        lsum += p[32];
        const float inv = 1.0f / lsum;
        float* op = out + (((size_t)b * 2048 + (qbase + l31)) * 16 + hh) * 64;
        #pragma unroll
        for (int dt = 0; dt < 2; ++dt)
            #pragma unroll
            for (int jq = 0; jq < 4; ++jq) {
                float4 o;
                o.x = acc[dt][4 * jq + 0] * inv;
                o.y = acc[dt][4 * jq + 1] * inv;
                o.z = acc[dt][4 * jq + 2] * inv;
                o.w = acc[dt][4 * jq + 3] * inv;
                *(float4*)(op + dt * 32 + 8 * jq + 4 * h) = o;
            }
    }
}

extern "C" void kernel_launch(void* const* d_in, const int* in_sizes, int n_in,
                              void* d_out, int out_size, void* d_ws, size_t ws_size,
                              hipStream_t stream) {
    const float* qkv = (const float*)d_in[0];
    const int* layout = (const int*)d_in[1];
    float* out = (float*)d_out;
    fba_fwd<<<dim3(1024), dim3(256), 0, stream>>>(qkv, layout, out);
}